// Round 1
// 703.237 us; speedup vs baseline: 1.0442x; 1.0442x over previous
//
#include <hip/hip_runtime.h>

// ---------- types ----------
typedef __attribute__((ext_vector_type(8))) short     bf16x8;   // MFMA A/B frag (4 VGPRs)
typedef __attribute__((ext_vector_type(4))) float     f32x4;    // MFMA C/D frag
typedef __attribute__((ext_vector_type(4))) unsigned short ushort4_t;

// B=512, T=256, D=256, H=128, 4H=512
#define BSZ   512
#define TSZ   256
#define DSZ   256
#define HSZ   128
#define G4    512
#define OUT1  16777216L  // B*T*H

// ---------- helpers ----------
__device__ inline unsigned short f2bf(float f) {
  union { float f; unsigned int u; } v; v.f = f;
  unsigned int r = (v.u + 0x7FFFu + ((v.u >> 16) & 1u)) >> 16;
  return (unsigned short)r;
}
__device__ inline float bf2f(unsigned int s) {
  union { unsigned int u; float f; } v; v.u = s << 16;
  return v.f;
}
__device__ inline float sig_fast(float x)  { return 1.0f / (1.0f + __expf(-x)); }
__device__ inline float tanh_fast(float x) { return 1.0f - 2.0f / (__expf(2.0f * x) + 1.0f); }

// ---------- kernel 1: xw[t][b][4H] = x[b,t,:] @ Wx.T + b (bf16 MFMA, fp32 acc) ----------
// Same tiling as before; output layout changed to [T][B][4H] bf16 so the scan
// reads one contiguous 512KB slab per step via uniform base + imm offsets.
__global__ __launch_bounds__(256)
void gemm_xw(const float* __restrict__ x, const float* __restrict__ Wx,
             const float* __restrict__ bias, unsigned short* __restrict__ xw) {
  __shared__ unsigned short aF[16384];
  __shared__ unsigned short bF[16384];

  const int tid   = threadIdx.x;
  const long mBase = (long)blockIdx.y * 64;   // M on y (slow)
  const int  nBase = blockIdx.x * 64;         // N on x (fast) -> same-M blocks adjacent

  const float* aSrc = x  + mBase * DSZ;
  const float* bSrc = Wx + (long)nBase * DSZ;

#pragma unroll
  for (int i = 0; i < 16; ++i) {
    int e  = i * 1024 + tid * 4;
    int m  = e >> 8, k = e & 255;
    int c  = k >> 5, kk = k & 31;
    int ln = (m & 15) | ((kk >> 3) << 4);
    int j  = kk & 7;
    int mt = m >> 4;
    int dst = (((c << 2) + mt) * 64 + ln) * 8 + j;
    float4 va = *(const float4*)(aSrc + e);
    float4 vb = *(const float4*)(bSrc + e);
    ushort4_t pa, pb;
    pa.x = f2bf(va.x); pa.y = f2bf(va.y); pa.z = f2bf(va.z); pa.w = f2bf(va.w);
    pb.x = f2bf(vb.x); pb.y = f2bf(vb.y); pb.z = f2bf(vb.z); pb.w = f2bf(vb.w);
    *(ushort4_t*)&aF[dst] = pa;
    *(ushort4_t*)&bF[dst] = pb;
  }
  __syncthreads();

  const int w = tid >> 6, lane = tid & 63;
  f32x4 acc[4];
#pragma unroll
  for (int nt = 0; nt < 4; ++nt) acc[nt] = (f32x4){0.f, 0.f, 0.f, 0.f};

#pragma unroll
  for (int c = 0; c < 8; ++c) {
    bf16x8 av = *(const bf16x8*)&aF[(((c << 2) + w) * 64 + lane) * 8];
#pragma unroll
    for (int nt = 0; nt < 4; ++nt) {
      bf16x8 bv = *(const bf16x8*)&bF[(((c << 2) + nt) * 64 + lane) * 8];
      acc[nt] = __builtin_amdgcn_mfma_f32_16x16x32_bf16(av, bv, acc[nt], 0, 0, 0);
    }
  }

  const int colLoc = lane & 15, rowQ = lane >> 4;
#pragma unroll
  for (int nt = 0; nt < 4; ++nt) {
    int n = nBase + nt * 16 + colLoc;
    float bv = bias[n];
#pragma unroll
    for (int r = 0; r < 4; ++r) {
      long m = mBase + w * 16 + rowQ * 4 + r;       // m = b*T + t
      long row = (m & (TSZ - 1)) * BSZ + (m >> 8);  // [t][b]
      xw[row * (long)G4 + n] = f2bf(acc[nt][r] + bv);
    }
  }
}

// ---------- kernel 2: recurrent scan via MFMA ----------
// 256 blocks x 512 threads (8 waves). Block owns 2 batches (MFMA rows 0,1).
// Changes vs previous version:
//  * raw s_barrier + explicit lgkmcnt(0): global prefetch loads / store-acks are
//    NOT drained at the per-step barrier (was s_waitcnt vmcnt(0) every step).
//  * xw in [T][B][4H]: one uniform SGPR slab pointer (+1 s_add/step); all 8
//    bf16 loads are imm offsets off a single per-lane voffset.
//  * output pointers uniform (SGPR base + lane voffset), advanced on SALU.
//  * acc[q][2..3] provably stay 0 (A rows 2-15 zero) -> only elements 0,1 are
//    rewritten each step (8 shl), no zero-fill movs.
//  * 2x unrolled body (xvA/xvB) -> no register copies, constant LDS addrs.
__global__ __launch_bounds__(512, 2)
void lstm_rec_mfma(const unsigned short* __restrict__ xw, const float* __restrict__ Wh,
                   float* __restrict__ outH, float* __restrict__ outC,
                   float* __restrict__ outP) {
  __shared__ unsigned short h_lds[2 * 2048];   // [buf][c(4)][lane(64)][j(8)] bf16

  const int tid  = threadIdx.x;
  const int w    = tid >> 6;        // wave 0..7
  const int lane = tid & 63;
  const int p    = lane & 15;
  const int r16  = lane >> 4;       // 0..3
  const int b0   = blockIdx.x * 2;

  // Wh -> B-frags (one-time). B[n=lane&15][k=(lane>>4)*8+j], n = q*128 + w*16 + p.
  bf16x8 whF[4][4];                 // [quadrant q][k-chunk c]
#pragma unroll
  for (int q = 0; q < 4; ++q) {
#pragma unroll
    for (int c = 0; c < 4; ++c) {
      const float* src = Wh + ((q * 128 + w * 16 + p) * HSZ + c * 32 + r16 * 8);
      float4 lo = *(const float4*)src;
      float4 hi = *(const float4*)(src + 4);
      bf16x8 f;
      f[0] = (short)f2bf(lo.x); f[1] = (short)f2bf(lo.y);
      f[2] = (short)f2bf(lo.z); f[3] = (short)f2bf(lo.w);
      f[4] = (short)f2bf(hi.x); f[5] = (short)f2bf(hi.y);
      f[6] = (short)f2bf(hi.z); f[7] = (short)f2bf(hi.w);
      whF[q][c] = f;
    }
  }

  // zero both h buffers (rows 2-15 stay zero forever)
  for (int i = tid; i < 2 * 2048; i += 512) h_lds[i] = 0;

  float cel0 = 0.f, cel1 = 0.f, pog0 = 0.f, pog1 = 0.f;

  const int colw = w * 16 + p;      // h/gate column owned by this lane
  // LDS write element offsets for h rows 0,1 in A-frag layout (per-lane consts)
  const int c_  = colw >> 5, kk = colw & 31;
  const int lhi = (kk >> 3) << 4, jj = kk & 7;
  const int wr0 = c_ * 512 + (0 | lhi) * 8 + jj;
  const int wr1 = c_ * 512 + (1 | lhi) * 8 + jj;

  // uniform slab pointer (SGPR) + per-lane offset; strides are imm offsets
  const unsigned short* xp = xw + (long)b0 * G4;   // t=0 slab, this block's 2 rows
  const long XSTR = (long)BSZ * G4;

  unsigned int xvA[8], xvB[8];
#pragma unroll
  for (int q = 0; q < 4; ++q) {
    xvA[2 * q]     = xp[colw + q * 128];
    xvA[2 * q + 1] = xp[colw + G4 + q * 128];
  }
  xp += XSTR;   // -> t=1

  // uniform output row pointers, advanced by HSZ per step (SALU)
  float* pH0 = outH + (long)b0 * TSZ * HSZ;
  float* pC0 = outC + (long)b0 * TSZ * HSZ;
  float* pP0 = outP + (long)b0 * TSZ * HSZ;
  float* pH1 = pH0 + (long)TSZ * HSZ;
  float* pC1 = pC0 + (long)TSZ * HSZ;
  float* pP1 = pP0 + (long)TSZ * HSZ;

  f32x4 acc[4];
#pragma unroll
  for (int q = 0; q < 4; ++q) acc[q] = (f32x4){0.f, 0.f, 0.f, 0.f};

  __syncthreads();

#define STEP(RDOFF, WROFF, XC, XN, PREF)                                        \
  {                                                                             \
    bf16x8 aF[4];                                                               \
    _Pragma("unroll")                                                           \
    for (int c = 0; c < 4; ++c)                                                 \
      aF[c] = *(const bf16x8*)&h_lds[(RDOFF) + c * 512 + lane * 8];             \
    if (PREF) {                                                                 \
      _Pragma("unroll")                                                         \
      for (int q = 0; q < 4; ++q) {                                             \
        XN[2 * q]     = xp[colw + q * 128];                                     \
        XN[2 * q + 1] = xp[colw + G4 + q * 128];                                \
      }                                                                         \
      xp += XSTR;                                                               \
    }                                                                           \
    _Pragma("unroll")                                                           \
    for (int q = 0; q < 4; ++q) {                                               \
      acc[q][0] = bf2f(XC[2 * q]);                                              \
      acc[q][1] = bf2f(XC[2 * q + 1]);                                          \
    }                                                                           \
    _Pragma("unroll")                                                           \
    for (int q = 0; q < 4; ++q)                                                 \
      _Pragma("unroll")                                                         \
      for (int c = 0; c < 4; ++c)                                               \
        acc[q] = __builtin_amdgcn_mfma_f32_16x16x32_bf16(aF[c], whF[q][c], acc[q], 0, 0, 0); \
    float i0 = sig_fast(acc[0][0]), i1 = sig_fast(acc[0][1]);                   \
    float f0 = sig_fast(acc[1][0]), f1 = sig_fast(acc[1][1]);                   \
    float s0 = sig_fast(acc[2][0]), s1 = sig_fast(acc[2][1]);                   \
    float o0 = 0.85f * s0 + 0.15f * pog0, o1 = 0.85f * s1 + 0.15f * pog1;       \
    float g0 = tanh_fast(acc[3][0]), g1 = tanh_fast(acc[3][1]);                 \
    cel0 = f0 * cel0 + i0 * g0; cel1 = f1 * cel1 + i1 * g1;                     \
    float h0 = o0 * tanh_fast(cel0), h1 = o1 * tanh_fast(cel1);                 \
    pog0 = o0; pog1 = o1;                                                       \
    if (lane < 16) {                                                            \
      pH0[colw] = h0; pC0[colw] = cel0; pP0[colw] = o0;                         \
      pH1[colw] = h1; pC1[colw] = cel1; pP1[colw] = o1;                         \
      h_lds[(WROFF) + wr0] = f2bf(h0);                                          \
      h_lds[(WROFF) + wr1] = f2bf(h1);                                          \
    }                                                                           \
    pH0 += HSZ; pC0 += HSZ; pP0 += HSZ;                                         \
    pH1 += HSZ; pC1 += HSZ; pP1 += HSZ;                                         \
    asm volatile("s_waitcnt lgkmcnt(0)" ::: "memory");  /* LDS drained only */  \
    __builtin_amdgcn_s_barrier();                       /* no vmcnt(0) drain */ \
  }

  for (int it = 0; it < 127; ++it) {    // t = 0..253
    STEP(0, 2048, xvA, xvB, true)
    STEP(2048, 0, xvB, xvA, true)
  }
  STEP(0, 2048, xvA, xvB, true)         // t = 254 (prefetch 255)
  STEP(2048, 0, xvB, xvA, false)        // t = 255 (no prefetch)
#undef STEP
}

// ---------- launch ----------
extern "C" void kernel_launch(void* const* d_in, const int* in_sizes, int n_in,
                              void* d_out, int out_size, void* d_ws, size_t ws_size,
                              hipStream_t stream) {
  const float* x    = (const float*)d_in[0];
  const float* Wx   = (const float*)d_in[1];
  const float* Wh   = (const float*)d_in[2];
  const float* bias = (const float*)d_in[3];

  float* outH = (float*)d_out;
  float* outC = outH + OUT1;
  float* outP = outC + OUT1;

  unsigned short* xwp = (unsigned short*)d_ws;  // bf16 xw, [T][B][4H], 134 MB

  dim3 g1(8, 2048), tb1(256);   // N fastest -> x fetched once, reused via L2
  dim3 g2(256),     tb2(512);

  gemm_xw<<<g1, tb1, 0, stream>>>(x, Wx, bias, xwp);
  lstm_rec_mfma<<<g2, tb2, 0, stream>>>(xwp, Wh, outH, outC, outP);
}

// Round 2
// 585.754 us; speedup vs baseline: 1.2536x; 1.2006x over previous
//
#include <hip/hip_runtime.h>

// ---------- types ----------
typedef __attribute__((ext_vector_type(8))) short     bf16x8;   // MFMA A/B frag (4 VGPRs)
typedef __attribute__((ext_vector_type(4))) float     f32x4;    // MFMA C/D frag

// B=512, T=256, D=256, H=128, 4H=512
#define BSZ   512
#define TSZ   256
#define DSZ   256
#define HSZ   128
#define G4    512
#define OUT1  16777216L  // B*T*H

// ---------- helpers ----------
__device__ inline unsigned short f2bf(float f) {
  union { float f; unsigned int u; } v; v.f = f;
  unsigned int r = (v.u + 0x7FFFu + ((v.u >> 16) & 1u)) >> 16;
  return (unsigned short)r;
}
__device__ inline float bf2f(unsigned int s) {
  union { unsigned int u; float f; } v; v.u = s << 16;
  return v.f;
}
__device__ inline float sig_fast(float x)  { return 1.0f / (1.0f + __expf(-x)); }
__device__ inline float tanh_fast(float x) { return 1.0f - 2.0f / (__expf(2.0f * x) + 1.0f); }

// ---------- kernel 1 (v2): xw[t][b][4H] = x[b,t,:] @ Wx.T + b ----------
// 256 blocks x 512 threads (8 waves). Block owns M-rows [blk*512, blk*512+512)
// and ALL N=512 gate columns:
//   * Wx lives in REGISTERS: wave w holds B-frags for n in [64w, 64w+64)
//     (4 n-tiles x 8 k-chunks = 32 bf16x8 = 128 VGPR). Converted once, not 2048x.
//   * x is read EXACTLY ONCE from HBM (no cross-block A-tile sharing -> no
//     cross-XCD L2 refetch, which made the old (8,2048)-grid version ~5x over
//     its memory roofline).
//   * A staged per 16-row tile via 16KB double-buffered LDS. Thread (w,l)
//     loads row (l&15), k-octet (4w + (l>>4)) => frag chunk c=w, frag lane=l:
//     the ds_write_b128 is EXACTLY lane-linear (conflict-free; the old
//     staging put a whole wave into a 4-bank window = ~16-way conflict).
//     Global read side: 16 segments x 128B full lines per wave.
//   * raw s_barrier + lgkmcnt(0) only (one per iter): next tile's global
//     loads stay in flight across the barrier.
__global__ __launch_bounds__(512, 2)
void gemm_xw(const float* __restrict__ x, const float* __restrict__ Wx,
             const float* __restrict__ bias, unsigned short* __restrict__ xw) {
  __shared__ unsigned short aT[2][4096];   // [dbuf][(c*64 + lane)*8 + j], 8KB each

  const int tid = threadIdx.x;
  const int w   = tid >> 6;        // wave 0..7  (owns n-cols [64w,64w+64), stages chunk c=w)
  const int l   = tid & 63;
  const int p   = l & 15;
  const int r16 = l >> 4;          // 0..3
  const long m0blk = (long)blockIdx.x * 512;

  // ---- Wx -> resident B-frags (one-time) ----
  bf16x8 wf[4][8];                 // [n-tile][k-chunk]
#pragma unroll
  for (int nt = 0; nt < 4; ++nt) {
#pragma unroll
    for (int c = 0; c < 8; ++c) {
      const float* src = Wx + (long)(w * 64 + nt * 16 + p) * DSZ + c * 32 + r16 * 8;
      float4 lo = *(const float4*)src;
      float4 hi = *(const float4*)(src + 4);
      bf16x8 f;
      f[0] = (short)f2bf(lo.x); f[1] = (short)f2bf(lo.y);
      f[2] = (short)f2bf(lo.z); f[3] = (short)f2bf(lo.w);
      f[4] = (short)f2bf(hi.x); f[5] = (short)f2bf(hi.y);
      f[6] = (short)f2bf(hi.z); f[7] = (short)f2bf(hi.w);
      wf[nt][c] = f;
    }
  }
  float bn[4];
#pragma unroll
  for (int nt = 0; nt < 4; ++nt) bn[nt] = bias[w * 64 + nt * 16 + p];

  // ---- staging source: row = l&15, k-octet = 4w + r16 ----
  const float* asrc = x + (m0blk + (l & 15)) * DSZ + (4 * w + r16) * 8;
  const int wl8 = (w * 64 + l) * 8;          // ushort index of this thread's LDS dst

  // prologue: load tile 0
  float4 va = *(const float4*)asrc;
  float4 vb = *(const float4*)(asrc + 4);
  asrc += 16 * DSZ;

  for (int i = 0; i < 32; ++i) {
    // convert + lane-linear b128 write of tile i
    bf16x8 fr;
    fr[0] = (short)f2bf(va.x); fr[1] = (short)f2bf(va.y);
    fr[2] = (short)f2bf(va.z); fr[3] = (short)f2bf(va.w);
    fr[4] = (short)f2bf(vb.x); fr[5] = (short)f2bf(vb.y);
    fr[6] = (short)f2bf(vb.z); fr[7] = (short)f2bf(vb.w);
    *(bf16x8*)&aT[i & 1][wl8] = fr;

    // prefetch tile i+1 (stays in flight across the barrier)
    if (i < 31) {
      va = *(const float4*)asrc;
      vb = *(const float4*)(asrc + 4);
      asrc += 16 * DSZ;
    }

    asm volatile("s_waitcnt lgkmcnt(0)" ::: "memory");  // LDS write drained only
    __builtin_amdgcn_s_barrier();                       // no vmcnt(0) drain

    // compute tile i: 16 M-rows x 512 N
    f32x4 acc[4];
#pragma unroll
    for (int nt = 0; nt < 4; ++nt)
      acc[nt] = (f32x4){bn[nt], bn[nt], bn[nt], bn[nt]};

#pragma unroll
    for (int c = 0; c < 8; ++c) {
      bf16x8 aF = *(const bf16x8*)&aT[i & 1][(c * 64 + l) * 8];
#pragma unroll
      for (int nt = 0; nt < 4; ++nt)
        acc[nt] = __builtin_amdgcn_mfma_f32_16x16x32_bf16(aF, wf[nt][c], acc[nt], 0, 0, 0);
    }

    // store: m = blk*512 + i*16 + r16*4 + r -> t = (i&15)*16 + r16*4 + r, b = blk*2 + (i>>4)
    const long rowbase = ((long)((i & 15) * 16 + r16 * 4) * BSZ + (blockIdx.x * 2 + (i >> 4))) * G4
                         + w * 64 + p;
#pragma unroll
    for (int r = 0; r < 4; ++r) {
      const long rb = rowbase + (long)r * (BSZ * G4);
#pragma unroll
      for (int nt = 0; nt < 4; ++nt)
        xw[rb + nt * 16] = f2bf(acc[nt][r]);
    }
  }
}

// ---------- kernel 2: recurrent scan via MFMA (unchanged from R1) ----------
__global__ __launch_bounds__(512, 2)
void lstm_rec_mfma(const unsigned short* __restrict__ xw, const float* __restrict__ Wh,
                   float* __restrict__ outH, float* __restrict__ outC,
                   float* __restrict__ outP) {
  __shared__ unsigned short h_lds[2 * 2048];   // [buf][c(4)][lane(64)][j(8)] bf16

  const int tid  = threadIdx.x;
  const int w    = tid >> 6;        // wave 0..7
  const int lane = tid & 63;
  const int p    = lane & 15;
  const int r16  = lane >> 4;       // 0..3
  const int b0   = blockIdx.x * 2;

  // Wh -> B-frags (one-time). B[n=lane&15][k=(lane>>4)*8+j], n = q*128 + w*16 + p.
  bf16x8 whF[4][4];                 // [quadrant q][k-chunk c]
#pragma unroll
  for (int q = 0; q < 4; ++q) {
#pragma unroll
    for (int c = 0; c < 4; ++c) {
      const float* src = Wh + ((q * 128 + w * 16 + p) * HSZ + c * 32 + r16 * 8);
      float4 lo = *(const float4*)src;
      float4 hi = *(const float4*)(src + 4);
      bf16x8 f;
      f[0] = (short)f2bf(lo.x); f[1] = (short)f2bf(lo.y);
      f[2] = (short)f2bf(lo.z); f[3] = (short)f2bf(lo.w);
      f[4] = (short)f2bf(hi.x); f[5] = (short)f2bf(hi.y);
      f[6] = (short)f2bf(hi.z); f[7] = (short)f2bf(hi.w);
      whF[q][c] = f;
    }
  }

  // zero both h buffers (rows 2-15 stay zero forever)
  for (int i = tid; i < 2 * 2048; i += 512) h_lds[i] = 0;

  float cel0 = 0.f, cel1 = 0.f, pog0 = 0.f, pog1 = 0.f;

  const int colw = w * 16 + p;      // h/gate column owned by this lane
  const int c_  = colw >> 5, kk = colw & 31;
  const int lhi = (kk >> 3) << 4, jj = kk & 7;
  const int wr0 = c_ * 512 + (0 | lhi) * 8 + jj;
  const int wr1 = c_ * 512 + (1 | lhi) * 8 + jj;

  const unsigned short* xp = xw + (long)b0 * G4;   // t=0 slab, this block's 2 rows
  const long XSTR = (long)BSZ * G4;

  unsigned int xvA[8], xvB[8];
#pragma unroll
  for (int q = 0; q < 4; ++q) {
    xvA[2 * q]     = xp[colw + q * 128];
    xvA[2 * q + 1] = xp[colw + G4 + q * 128];
  }
  xp += XSTR;   // -> t=1

  float* pH0 = outH + (long)b0 * TSZ * HSZ;
  float* pC0 = outC + (long)b0 * TSZ * HSZ;
  float* pP0 = outP + (long)b0 * TSZ * HSZ;
  float* pH1 = pH0 + (long)TSZ * HSZ;
  float* pC1 = pC0 + (long)TSZ * HSZ;
  float* pP1 = pP0 + (long)TSZ * HSZ;

  f32x4 acc[4];
#pragma unroll
  for (int q = 0; q < 4; ++q) acc[q] = (f32x4){0.f, 0.f, 0.f, 0.f};

  __syncthreads();

#define STEP(RDOFF, WROFF, XC, XN, PREF)                                        \
  {                                                                             \
    bf16x8 aF[4];                                                               \
    _Pragma("unroll")                                                           \
    for (int c = 0; c < 4; ++c)                                                 \
      aF[c] = *(const bf16x8*)&h_lds[(RDOFF) + c * 512 + lane * 8];             \
    if (PREF) {                                                                 \
      _Pragma("unroll")                                                         \
      for (int q = 0; q < 4; ++q) {                                             \
        XN[2 * q]     = xp[colw + q * 128];                                     \
        XN[2 * q + 1] = xp[colw + G4 + q * 128];                                \
      }                                                                         \
      xp += XSTR;                                                               \
    }                                                                           \
    _Pragma("unroll")                                                           \
    for (int q = 0; q < 4; ++q) {                                               \
      acc[q][0] = bf2f(XC[2 * q]);                                              \
      acc[q][1] = bf2f(XC[2 * q + 1]);                                          \
    }                                                                           \
    _Pragma("unroll")                                                           \
    for (int q = 0; q < 4; ++q)                                                 \
      _Pragma("unroll")                                                         \
      for (int c = 0; c < 4; ++c)                                               \
        acc[q] = __builtin_amdgcn_mfma_f32_16x16x32_bf16(aF[c], whF[q][c], acc[q], 0, 0, 0); \
    float i0 = sig_fast(acc[0][0]), i1 = sig_fast(acc[0][1]);                   \
    float f0 = sig_fast(acc[1][0]), f1 = sig_fast(acc[1][1]);                   \
    float s0 = sig_fast(acc[2][0]), s1 = sig_fast(acc[2][1]);                   \
    float o0 = 0.85f * s0 + 0.15f * pog0, o1 = 0.85f * s1 + 0.15f * pog1;       \
    float g0 = tanh_fast(acc[3][0]), g1 = tanh_fast(acc[3][1]);                 \
    cel0 = f0 * cel0 + i0 * g0; cel1 = f1 * cel1 + i1 * g1;                     \
    float h0 = o0 * tanh_fast(cel0), h1 = o1 * tanh_fast(cel1);                 \
    pog0 = o0; pog1 = o1;                                                       \
    if (lane < 16) {                                                            \
      pH0[colw] = h0; pC0[colw] = cel0; pP0[colw] = o0;                         \
      pH1[colw] = h1; pC1[colw] = cel1; pP1[colw] = o1;                         \
      h_lds[(WROFF) + wr0] = f2bf(h0);                                          \
      h_lds[(WROFF) + wr1] = f2bf(h1);                                          \
    }                                                                           \
    pH0 += HSZ; pC0 += HSZ; pP0 += HSZ;                                         \
    pH1 += HSZ; pC1 += HSZ; pP1 += HSZ;                                         \
    asm volatile("s_waitcnt lgkmcnt(0)" ::: "memory");  /* LDS drained only */  \
    __builtin_amdgcn_s_barrier();                       /* no vmcnt(0) drain */ \
  }

  for (int it = 0; it < 127; ++it) {    // t = 0..253
    STEP(0, 2048, xvA, xvB, true)
    STEP(2048, 0, xvB, xvA, true)
  }
  STEP(0, 2048, xvA, xvB, true)         // t = 254 (prefetch 255)
  STEP(2048, 0, xvB, xvA, false)        // t = 255 (no prefetch)
#undef STEP
}

// ---------- launch ----------
extern "C" void kernel_launch(void* const* d_in, const int* in_sizes, int n_in,
                              void* d_out, int out_size, void* d_ws, size_t ws_size,
                              hipStream_t stream) {
  const float* x    = (const float*)d_in[0];
  const float* Wx   = (const float*)d_in[1];
  const float* Wh   = (const float*)d_in[2];
  const float* bias = (const float*)d_in[3];

  float* outH = (float*)d_out;
  float* outC = outH + OUT1;
  float* outP = outC + OUT1;

  unsigned short* xwp = (unsigned short*)d_ws;  // bf16 xw, [T][B][4H], 134 MB

  dim3 g1(256), tb1(512);
  dim3 g2(256), tb2(512);

  gemm_xw<<<g1, tb1, 0, stream>>>(x, Wx, bias, xwp);
  lstm_rec_mfma<<<g2, tb2, 0, stream>>>(xwp, Wh, outH, outC, outP);
}